// Round 1
// baseline (1076.430 us; speedup 1.0000x reference)
//
#include <hip/hip_runtime.h>
#include <cstdint>

typedef __bf16 bf16_t;
typedef __bf16 bf16x4 __attribute__((ext_vector_type(4)));
typedef __bf16 bf16x8 __attribute__((ext_vector_type(8)));
typedef float  f32x4  __attribute__((ext_vector_type(4)));

#define TOTAL_BINS 28749
#define WH_LD      29048   // sum of round_up(L_i, 32)
#define N_HEADS    22
#define BATCH      2048
#define ROWS       4096    // BATCH * 2 channels
#define IDIM       2200
#define IDIM_P     2208    // K pad (mult of 32)
#define IDIM_NP    2304    // N pad (18 * 128)
#define H1DIM      1000
#define H1_NP      1024
#define H2DIM      50
#define H2_P       64
#define ODIM       13

// chromosome bin offsets (cumsum) and 32-aligned packed offsets for head_w copy
__constant__ int d_LOC[23] = {0,2490,4912,6895,8797,10612,12320,13913,15364,16748,
                              18086,19437,20770,21914,22984,24004,24907,25740,26544,
                              27130,27774,28241,28749};
__constant__ int d_HA[23]  = {0,2496,4928,6912,8832,10656,12384,13984,15440,16824,
                              18168,19544,20888,22040,23128,24152,25080,25944,26776,
                              27384,28056,28536,29048};

__device__ __forceinline__ void g2lds16(const void* g, void* l) {
  __builtin_amdgcn_global_load_lds((const __attribute__((address_space(1))) void*)g,
                                   (__attribute__((address_space(3))) void*)l, 16, 0, 0);
}

// ---------- weight conversion: fp32 (rows x cols) -> bf16 (prow x pcol), zero padded ----------
__global__ __launch_bounds__(256) void convert_pad(const float* __restrict__ src,
                                                   bf16_t* __restrict__ dst,
                                                   int rows, int cols, int prow, int pcol)
{
  size_t i = (size_t)blockIdx.x * 256 + threadIdx.x;
  size_t total = (size_t)prow * pcol;
  if (i >= total) return;
  int r = (int)(i / pcol);
  int c = (int)(i - (size_t)r * pcol);
  float v = (r < rows && c < cols) ? src[(size_t)r * cols + c] : 0.0f;
  dst[i] = (bf16_t)v;
}

// ---------- head_w repack: (50 x 28749) -> (64 x WH_LD) bf16, per-head 32-aligned, zero pad ----------
__global__ __launch_bounds__(256) void convert_headw(const float* __restrict__ src,
                                                     bf16_t* __restrict__ dst)
{
  size_t i = (size_t)blockIdx.x * 256 + threadIdx.x;
  if (i >= (size_t)64 * WH_LD) return;
  int r = (int)(i / WH_LD);
  int c = (int)(i - (size_t)r * WH_LD);
  float v = 0.0f;
  #pragma unroll
  for (int h = 0; h < N_HEADS; h++) {
    int ha = d_HA[h], hb = d_HA[h + 1];
    if (c >= ha && c < hb) {
      int k = c - ha;
      int a = d_LOC[h];
      int L = d_LOC[h + 1] - a;
      if (r < 50 && k < L) v = src[(size_t)r * TOTAL_BINS + a + k];
    }
  }
  dst[i] = (bf16_t)v;
}

// ---------- stage 1: per-head GEMM  H[r, o] = sum_k X[r, a+k] * Wh[o, ha+k]  (+bias, scatter) ----
// grid: (ROWS/128, N_HEADS); block 256 = 4 waves; wave tile 32x64; BK=32
__global__ __launch_bounds__(256) void head_gemm(const float* __restrict__ X,
                                                 const bf16_t* __restrict__ Wh,
                                                 const float* __restrict__ headb,
                                                 bf16_t* __restrict__ Cmb)
{
  __shared__ __attribute__((aligned(16))) bf16_t As[128][32];
  __shared__ __attribute__((aligned(16))) bf16_t Bs[64][32];
  const int tid  = threadIdx.x;
  const int lane = tid & 63, wid = tid >> 6;
  const int head = blockIdx.y;
  const int a    = d_LOC[head];
  const int L    = d_LOC[head + 1] - a;
  const int ha   = d_HA[head];
  const int m0   = blockIdx.x * 128;
  const int la = lane & 15, lk = lane >> 4;

  f32x4 acc[2][4] = {};

  const bf16x8* AsV = (const bf16x8*)(&As[0][0]);
  const bf16x8* BsV = (const bf16x8*)(&Bs[0][0]);

  const bf16_t* wsrc = Wh + (size_t)(tid >> 2) * WH_LD + ha + (tid & 3) * 8;
  bf16_t* bdst = &Bs[0][0] + tid * 8;

  for (int k0 = 0; k0 < L; k0 += 32) {
    __syncthreads();
    g2lds16(wsrc + k0, bdst);                       // 64x32 bf16 W tile (async)
    const bool full = (k0 + 32 <= L);
    #pragma unroll
    for (int rr = 0; rr < 4; rr++) {                // 128x32 fp32 A tile -> cvt -> LDS
      int q = rr * 256 + tid;
      int row = q >> 3, cc = (q & 7) * 4;
      const float* src = X + (size_t)(m0 + row) * TOTAL_BINS + a + k0 + cc;
      float f0, f1, f2, f3;
      if (full) { f0 = src[0]; f1 = src[1]; f2 = src[2]; f3 = src[3]; }
      else {
        int kk = k0 + cc;
        f0 = (kk + 0 < L) ? src[0] : 0.0f;
        f1 = (kk + 1 < L) ? src[1] : 0.0f;
        f2 = (kk + 2 < L) ? src[2] : 0.0f;
        f3 = (kk + 3 < L) ? src[3] : 0.0f;
      }
      bf16x4 v; v.x = (bf16_t)f0; v.y = (bf16_t)f1; v.z = (bf16_t)f2; v.w = (bf16_t)f3;
      *(bf16x4*)(&As[row][cc]) = v;
    }
    __syncthreads();
    bf16x8 af[2], bfr[4];
    #pragma unroll
    for (int i = 0; i < 2; i++) af[i]  = AsV[(wid * 32 + i * 16 + la) * 4 + lk];
    #pragma unroll
    for (int j = 0; j < 4; j++) bfr[j] = BsV[(j * 16 + la) * 4 + lk];
    #pragma unroll
    for (int i = 0; i < 2; i++)
      #pragma unroll
      for (int j = 0; j < 4; j++)
        acc[i][j] = __builtin_amdgcn_mfma_f32_16x16x32_bf16(af[i], bfr[j], acc[i][j], 0, 0, 0);
  }

  // epilogue: r = b*2+c row -> combined[b, head*100 + c*50 + o]
  #pragma unroll
  for (int j = 0; j < 4; j++) {
    int o = j * 16 + la;
    if (o < 50) {
      float bv = headb[head * 50 + o];
      #pragma unroll
      for (int i = 0; i < 2; i++) {
        #pragma unroll
        for (int r = 0; r < 4; r++) {
          int gr = m0 + wid * 32 + i * 16 + lk * 4 + r;
          int bidx = gr >> 1, ch = gr & 1;
          Cmb[(size_t)bidx * IDIM_P + head * 100 + ch * 50 + o] = (bf16_t)(acc[i][j][r] + bv);
        }
      }
    }
  }
}

// ---------- generic bf16 MFMA GEMM: C[m,n] = sum_k A[m,k] * W[n,k] + bias[n] ----------
// A: M x lda bf16 (M mult of 128), W: Npad x ldb bf16 (rows/cols zero-padded), K mult of 32
// grid: (M/128, Npad/128); block 256 = 4 waves (2x2), wave tile 64x64, BK=32
__global__ __launch_bounds__(256) void gemm_bt(const bf16_t* __restrict__ A, int lda,
                                               const bf16_t* __restrict__ W, int ldb,
                                               const float* __restrict__ bias,
                                               void* __restrict__ Cout, int ldc,
                                               int K, int N, int act, int out_f32)
{
  __shared__ __attribute__((aligned(16))) bf16_t As[128][32];
  __shared__ __attribute__((aligned(16))) bf16_t Bs[128][32];
  const int tid  = threadIdx.x;
  const int lane = tid & 63, wid = tid >> 6;
  const int m0 = blockIdx.x * 128;
  const int n0 = blockIdx.y * 128;
  const int wm = (wid >> 1) * 64, wn = (wid & 1) * 64;
  const int la = lane & 15, lk = lane >> 4;

  f32x4 acc[4][4] = {};

  const bf16_t* asrc0 = A + (size_t)(m0 + (tid >> 2)) * lda + (tid & 3) * 8;
  const bf16_t* asrc1 = asrc0 + (size_t)64 * lda;
  const bf16_t* wsrc0 = W + (size_t)(n0 + (tid >> 2)) * ldb + (tid & 3) * 8;
  const bf16_t* wsrc1 = wsrc0 + (size_t)64 * ldb;
  bf16_t* adst0 = &As[0][0] + tid * 8;
  bf16_t* adst1 = adst0 + 2048;
  bf16_t* bdst0 = &Bs[0][0] + tid * 8;
  bf16_t* bdst1 = bdst0 + 2048;

  const bf16x8* AsV = (const bf16x8*)(&As[0][0]);
  const bf16x8* BsV = (const bf16x8*)(&Bs[0][0]);

  for (int k0 = 0; k0 < K; k0 += 32) {
    __syncthreads();
    g2lds16(asrc0 + k0, adst0);
    g2lds16(asrc1 + k0, adst1);
    g2lds16(wsrc0 + k0, bdst0);
    g2lds16(wsrc1 + k0, bdst1);
    __syncthreads();
    bf16x8 af[4], bfr[4];
    #pragma unroll
    for (int i = 0; i < 4; i++) af[i]  = AsV[(wm + i * 16 + la) * 4 + lk];
    #pragma unroll
    for (int j = 0; j < 4; j++) bfr[j] = BsV[(wn + j * 16 + la) * 4 + lk];
    #pragma unroll
    for (int i = 0; i < 4; i++)
      #pragma unroll
      for (int j = 0; j < 4; j++)
        acc[i][j] = __builtin_amdgcn_mfma_f32_16x16x32_bf16(af[i], bfr[j], acc[i][j], 0, 0, 0);
  }

  float bv[4]; bool ok[4]; int gcv[4];
  #pragma unroll
  for (int j = 0; j < 4; j++) {
    int gc = n0 + wn + j * 16 + la;
    gcv[j] = gc; ok[j] = gc < N;
    bv[j] = ok[j] ? bias[gc] : 0.0f;
  }
  #pragma unroll
  for (int i = 0; i < 4; i++) {
    #pragma unroll
    for (int r = 0; r < 4; r++) {
      int gr = m0 + wm + i * 16 + lk * 4 + r;
      #pragma unroll
      for (int j = 0; j < 4; j++) {
        if (ok[j]) {
          float v = acc[i][j][r] + bv[j];
          if (act) v = fmaxf(v, 0.01f * v);      // leaky_relu(0.01)
          if (out_f32) ((float*) Cout)[(size_t)gr * ldc + gcv[j]] = v;
          else         ((bf16_t*)Cout)[(size_t)gr * ldc + gcv[j]] = (bf16_t)v;
        }
      }
    }
  }
}

extern "C" void kernel_launch(void* const* d_in, const int* in_sizes, int n_in,
                              void* d_out, int out_size, void* d_ws, size_t ws_size,
                              hipStream_t stream)
{
  const float* X      = (const float*)d_in[0];   // (2048, 2, 28749)
  const float* head_w = (const float*)d_in[1];   // (50, 28749)
  const float* head_b = (const float*)d_in[2];   // (22, 50)
  const float* conc_w = (const float*)d_in[3];   // (2200, 2200)
  const float* conc_b = (const float*)d_in[4];   // (2200,)
  const float* w1     = (const float*)d_in[5];   // (1000, 2200)
  const float* b1     = (const float*)d_in[6];
  const float* w2     = (const float*)d_in[7];   // (50, 1000)
  const float* b2     = (const float*)d_in[8];
  const float* w3     = (const float*)d_in[9];   // (13, 50)
  const float* b3     = (const float*)d_in[10];

  char* p = (char*)d_ws;
  auto alloc = [&](size_t bytes) { char* r = p; p += (bytes + 255) & ~(size_t)255; return r; };
  bf16_t* headw_ws = (bf16_t*)alloc((size_t)64 * WH_LD * 2);       // 3.7 MB
  bf16_t* concw_ws = (bf16_t*)alloc((size_t)IDIM_NP * IDIM_P * 2); // 10.2 MB
  bf16_t* w1_ws    = (bf16_t*)alloc((size_t)H1_NP * IDIM_P * 2);   // 4.5 MB
  bf16_t* w2_ws    = (bf16_t*)alloc((size_t)128 * H1_NP * 2);      // 0.26 MB
  bf16_t* w3_ws    = (bf16_t*)alloc((size_t)128 * H2_P * 2);       // 16 KB
  bf16_t* comb     = (bf16_t*)alloc((size_t)BATCH * IDIM_P * 2);   // 9.0 MB
  bf16_t* zbuf     = (bf16_t*)alloc((size_t)BATCH * IDIM_P * 2);   // 9.0 MB
  bf16_t* h1buf    = (bf16_t*)alloc((size_t)BATCH * H1_NP * 2);    // 4.2 MB
  bf16_t* h2buf    = (bf16_t*)alloc((size_t)BATCH * H2_P * 2);     // 0.26 MB
  // total ~41.2 MB of d_ws

  auto cgrid = [](size_t n) { return dim3((unsigned)((n + 255) / 256)); };

  convert_headw<<<cgrid((size_t)64 * WH_LD), 256, 0, stream>>>(head_w, headw_ws);
  convert_pad<<<cgrid((size_t)IDIM_NP * IDIM_P), 256, 0, stream>>>(conc_w, concw_ws, IDIM, IDIM, IDIM_NP, IDIM_P);
  convert_pad<<<cgrid((size_t)H1_NP * IDIM_P), 256, 0, stream>>>(w1, w1_ws, H1DIM, IDIM, H1_NP, IDIM_P);
  convert_pad<<<cgrid((size_t)128 * H1_NP), 256, 0, stream>>>(w2, w2_ws, H2DIM, H1DIM, 128, H1_NP);
  convert_pad<<<cgrid((size_t)128 * H2_P), 256, 0, stream>>>(w3, w3_ws, ODIM, H2DIM, 128, H2_P);

  // stage 1: heads -> combined (2048 x 2208 bf16; pad cols garbage, annihilated by zero K-pad of conc_w)
  head_gemm<<<dim3(ROWS / 128, N_HEADS), 256, 0, stream>>>(X, headw_ws, head_b, comb);

  // stage 2: z = combined @ conc_w^T + conc_b        (2048 x 2200, bf16)
  gemm_bt<<<dim3(BATCH / 128, IDIM_NP / 128), 256, 0, stream>>>(
      comb, IDIM_P, concw_ws, IDIM_P, conc_b, zbuf, IDIM_P, IDIM_P, IDIM, 0, 0);
  // stage 3: h1 = lrelu(z @ w1^T + b1)               (2048 x 1000, bf16)
  gemm_bt<<<dim3(BATCH / 128, H1_NP / 128), 256, 0, stream>>>(
      zbuf, IDIM_P, w1_ws, IDIM_P, b1, h1buf, H1_NP, IDIM_P, H1DIM, 1, 0);
  // stage 4: h2 = lrelu(h1 @ w2^T + b2)              (2048 x 50, bf16)
  gemm_bt<<<dim3(BATCH / 128, 1), 256, 0, stream>>>(
      h1buf, H1_NP, w2_ws, H1_NP, b2, h2buf, H2_P, H1_NP, H2DIM, 1, 0);
  // stage 5: out = h2 @ w3^T + b3                    (2048 x 13, fp32 -> d_out)
  gemm_bt<<<dim3(BATCH / 128, 1), 256, 0, stream>>>(
      h2buf, H2_P, w3_ws, H2_P, b3, d_out, ODIM, H2_P, ODIM, 0, 1);
}

// Round 2
// 878.469 us; speedup vs baseline: 1.2253x; 1.2253x over previous
//
#include <hip/hip_runtime.h>
#include <cstdint>

typedef __bf16 bf16_t;
typedef __bf16 bf16x4 __attribute__((ext_vector_type(4)));
typedef __bf16 bf16x8 __attribute__((ext_vector_type(8)));
typedef float  f32x4  __attribute__((ext_vector_type(4)));

#define TOTAL_BINS 28749
#define WH_LD64    29312   // sum of round_up(L_i, 64)
#define N_HEADS    22
#define BATCH      2048
#define ROWS       4096    // BATCH * 2 channels
#define IDIM       2200
#define IDIM_P     2208    // K pad (mult of 32)
#define IDIM_NP    2304    // N pad (18 * 128)
#define H1DIM      1000
#define H1_NP      1024
#define H2DIM      50
#define ODIM       13
#define KSPLIT     8

__constant__ int d_LOC[23]  = {0,2490,4912,6895,8797,10612,12320,13913,15364,16748,
                               18086,19437,20770,21914,22984,24004,24907,25740,26544,
                               27130,27774,28241,28749};
// per-head offsets rounded up to 64 (packing layout for head_w bf16 copy)
__constant__ int d_HA64[23] = {0,2496,4928,6912,8832,10688,12416,14016,15488,16896,
                               18240,19648,20992,22144,23232,24256,25216,26112,26944,
                               27584,28288,28800,29312};

__device__ __forceinline__ void g2lds16(const void* g, void* l) {
  __builtin_amdgcn_global_load_lds((const __attribute__((address_space(1))) void*)g,
                                   (__attribute__((address_space(3))) void*)l, 16, 0, 0);
}

__device__ __forceinline__ f32x4 mfma16(bf16x8 a, bf16x8 b, f32x4 c) {
  return __builtin_amdgcn_mfma_f32_16x16x32_bf16(a, b, c, 0, 0, 0);
}

// ---------- weight conversion: fp32 (rows x cols) -> bf16 (prow x pcol), zero padded ----------
__global__ __launch_bounds__(256) void convert_pad(const float* __restrict__ src,
                                                   bf16_t* __restrict__ dst,
                                                   int rows, int cols, int prow, int pcol)
{
  size_t i = (size_t)blockIdx.x * 256 + threadIdx.x;
  size_t total = (size_t)prow * pcol;
  if (i >= total) return;
  int r = (int)(i / pcol);
  int c = (int)(i - (size_t)r * pcol);
  float v = (r < rows && c < cols) ? src[(size_t)r * cols + c] : 0.0f;
  dst[i] = (bf16_t)v;
}

// ---------- head_w repack: (50 x 28749) -> (64 x WH_LD64) bf16, per-head 64-aligned, zero pad ----
__global__ __launch_bounds__(256) void convert_headw(const float* __restrict__ src,
                                                     bf16_t* __restrict__ dst)
{
  size_t i = (size_t)blockIdx.x * 256 + threadIdx.x;
  if (i >= (size_t)64 * WH_LD64) return;
  int r = (int)(i / WH_LD64);
  int c = (int)(i - (size_t)r * WH_LD64);
  float v = 0.0f;
  #pragma unroll
  for (int h = 0; h < N_HEADS; h++) {
    int ha = d_HA64[h], hb = d_HA64[h + 1];
    if (c >= ha && c < hb) {
      int k = c - ha;
      int a = d_LOC[h];
      int L = d_LOC[h + 1] - a;
      if (r < 50 && k < L) v = src[(size_t)r * TOTAL_BINS + a + k];
    }
  }
  dst[i] = (bf16_t)v;
}

// ---------- stage 1: per-head GEMM, A direct-to-reg (prefetched), W LDS double-buffered ----------
// grid (ROWS/64, 22); 256 thr = 4 waves; wave owns 16 rows x 64 cols; BK=64; 1 barrier/iter
__global__ __launch_bounds__(256) void head_gemm2(const float* __restrict__ X,
                                                  const bf16_t* __restrict__ Wh,
                                                  const float* __restrict__ headb,
                                                  bf16_t* __restrict__ Cmb)
{
  __shared__ __attribute__((aligned(16))) bf16_t Ws[2][64][72]; // +8 pad: bank-floor reads
  const int tid = threadIdx.x, lane = tid & 63, wid = tid >> 6;
  const int head = blockIdx.y;
  const int a   = d_LOC[head];
  const int ha  = d_HA64[head];
  const int L64 = d_HA64[head + 1] - ha;
  const int m0  = blockIdx.x * 64;
  const int la = lane & 15, lk = lane >> 4;
  const int wrow = m0 + wid * 16 + la;                 // A row this lane feeds
  const uint32_t rowbase = (uint32_t)wrow * TOTAL_BINS + (uint32_t)a;
  const uint32_t MAXO = (uint32_t)ROWS * TOTAL_BINS - 1;

  // W staging: thread t -> Wh row n=t>>2, 16 bf16 at kgrp=(t&3)*16
  const int sn = tid >> 2, skg = (tid & 3) * 16;
  const bf16_t* wsrc = Wh + (size_t)sn * WH_LD64 + ha + skg;

  f32x4 acc[4] = {};

  // prolog: W(0) -> Ws[0], prefetch A(0) to regs
  {
    uint4 w0 = *(const uint4*)(wsrc);
    uint4 w1 = *(const uint4*)(wsrc + 8);
    *(uint4*)(&Ws[0][sn][skg])     = w0;
    *(uint4*)(&Ws[0][sn][skg + 8]) = w1;
  }
  float ar[16];
  #pragma unroll
  for (int q = 0; q < 16; q++) {
    uint32_t o = rowbase + (uint32_t)((q >> 3) * 32 + lk * 8 + (q & 7));
    ar[q] = X[min(o, MAXO)];     // tail garbage annihilated by W zero-pad
  }

  const int nIter = L64 >> 6;
  for (int i = 0; i < nIter; i++) {
    __syncthreads();             // Ws[i&1] ready; prev g-loads drained
    const int cur = i & 1, nxt = cur ^ 1;
    uint4 nw0, nw1; float an[16];
    const bool more = (i + 1 < nIter);
    if (more) {                  // issue next-iter loads early (prefetch)
      const bf16_t* ws2 = wsrc + (size_t)(i + 1) * 64;
      nw0 = *(const uint4*)(ws2);
      nw1 = *(const uint4*)(ws2 + 8);
      uint32_t kb2 = rowbase + (uint32_t)(i + 1) * 64;
      #pragma unroll
      for (int q = 0; q < 16; q++) {
        uint32_t o = kb2 + (uint32_t)((q >> 3) * 32 + lk * 8 + (q & 7));
        an[q] = X[min(o, MAXO)];
      }
    }
    // convert current A to frags
    bf16x8 af[2];
    #pragma unroll
    for (int kq = 0; kq < 2; kq++)
      #pragma unroll
      for (int j = 0; j < 8; j++)
        af[kq][j] = (bf16_t)ar[kq * 8 + j];
    // B frags from LDS + MFMA
    #pragma unroll
    for (int kq = 0; kq < 2; kq++)
      #pragma unroll
      for (int j = 0; j < 4; j++) {
        bf16x8 bf = *(const bf16x8*)(&Ws[cur][j * 16 + la][kq * 32 + lk * 8]);
        acc[j] = mfma16(af[kq], bf, acc[j]);
      }
    if (more) {
      *(uint4*)(&Ws[nxt][sn][skg])     = nw0;
      *(uint4*)(&Ws[nxt][sn][skg + 8]) = nw1;
      #pragma unroll
      for (int q = 0; q < 16; q++) ar[q] = an[q];
    }
  }

  // epilogue: row = b*2+ch -> combined[b, head*100 + ch*50 + o]
  #pragma unroll
  for (int j = 0; j < 4; j++) {
    int o = j * 16 + la;
    if (o < 50) {
      float bv = headb[head * 50 + o];
      #pragma unroll
      for (int r = 0; r < 4; r++) {
        int gr = m0 + wid * 16 + lk * 4 + r;
        Cmb[(size_t)(gr >> 1) * IDIM_P + head * 100 + (gr & 1) * 50 + o] =
            (bf16_t)(acc[j][r] + bv);
      }
    }
  }
}

// ---------- generic bf16 MFMA GEMM, double-buffered g2lds, 1 barrier/iter ----------
// C[m,n] = sum_k A[m,k] * W[n,k] + bias[n]; 128x128 tile, BK=32
__global__ __launch_bounds__(256) void gemm_bt(const bf16_t* __restrict__ A, int lda,
                                               const bf16_t* __restrict__ W, int ldb,
                                               const float* __restrict__ bias,
                                               void* __restrict__ Cout, int ldc,
                                               int K, int N, int act, int out_f32)
{
  __shared__ __attribute__((aligned(16))) bf16_t As[2][128][32];
  __shared__ __attribute__((aligned(16))) bf16_t Bs[2][128][32];
  const int tid  = threadIdx.x;
  const int lane = tid & 63, wid = tid >> 6;
  const int m0 = blockIdx.x * 128;
  const int n0 = blockIdx.y * 128;
  const int wm = (wid >> 1) * 64, wn = (wid & 1) * 64;
  const int la = lane & 15, lk = lane >> 4;

  f32x4 acc[4][4] = {};

  const bf16_t* asrc0 = A + (size_t)(m0 + (tid >> 2)) * lda + (tid & 3) * 8;
  const bf16_t* asrc1 = asrc0 + (size_t)64 * lda;
  const bf16_t* wsrc0 = W + (size_t)(n0 + (tid >> 2)) * ldb + (tid & 3) * 8;
  const bf16_t* wsrc1 = wsrc0 + (size_t)64 * ldb;

  auto stage = [&](int buf, int k0) {
    g2lds16(asrc0 + k0, &As[buf][0][0] + tid * 8);
    g2lds16(asrc1 + k0, &As[buf][64][0] + tid * 8);
    g2lds16(wsrc0 + k0, &Bs[buf][0][0] + tid * 8);
    g2lds16(wsrc1 + k0, &Bs[buf][64][0] + tid * 8);
  };
  stage(0, 0);

  int i = 0;
  for (int k0 = 0; k0 < K; k0 += 32, i++) {
    __syncthreads();                       // drains vmcnt -> buf[i&1] ready
    const int cur = i & 1;
    if (k0 + 32 < K) stage(cur ^ 1, k0 + 32);
    bf16x8 af[4], bfr[4];
    #pragma unroll
    for (int ii = 0; ii < 4; ii++) af[ii]  = *(const bf16x8*)(&As[cur][wm + ii * 16 + la][lk * 8]);
    #pragma unroll
    for (int j = 0; j < 4; j++)    bfr[j] = *(const bf16x8*)(&Bs[cur][wn + j * 16 + la][lk * 8]);
    #pragma unroll
    for (int ii = 0; ii < 4; ii++)
      #pragma unroll
      for (int j = 0; j < 4; j++)
        acc[ii][j] = mfma16(af[ii], bfr[j], acc[ii][j]);
  }

  float bv[4]; bool ok[4]; int gcv[4];
  #pragma unroll
  for (int j = 0; j < 4; j++) {
    int gc = n0 + wn + j * 16 + la;
    gcv[j] = gc; ok[j] = gc < N;
    bv[j] = ok[j] ? bias[gc] : 0.0f;
  }
  #pragma unroll
  for (int ii = 0; ii < 4; ii++) {
    #pragma unroll
    for (int r = 0; r < 4; r++) {
      int gr = m0 + wm + ii * 16 + lk * 4 + r;
      #pragma unroll
      for (int j = 0; j < 4; j++) {
        if (ok[j]) {
          float v = acc[ii][j][r] + bv[j];
          if (act) v = fmaxf(v, 0.01f * v);
          if (out_f32) ((float*) Cout)[(size_t)gr * ldc + gcv[j]] = v;
          else         ((bf16_t*)Cout)[(size_t)gr * ldc + gcv[j]] = (bf16_t)v;
        }
      }
    }
  }
}

// ---------- stage 4 split-K: P[split][m][n] = sum_{k in chunk} h1[m,k]*w2[n,k] ----------
// grid (16, KSPLIT); 128x64 tile, wave = 32x64, BK=32, dbuf
__global__ __launch_bounds__(256) void gemm_splitk(const bf16_t* __restrict__ A,
                                                   const bf16_t* __restrict__ W,
                                                   float* __restrict__ P)
{
  __shared__ __attribute__((aligned(16))) bf16_t As[2][128][32];
  __shared__ __attribute__((aligned(16))) bf16_t Bs[2][64][32];
  const int tid  = threadIdx.x;
  const int lane = tid & 63, wid = tid >> 6;
  const int m0 = blockIdx.x * 128;
  const int split = blockIdx.y;
  const int kb = split * (H1_NP / KSPLIT);             // 128
  const int la = lane & 15, lk = lane >> 4;
  const int wm = wid * 32;

  f32x4 acc[2][4] = {};

  const bf16_t* asrc0 = A + (size_t)(m0 + (tid >> 2)) * H1_NP + kb + (tid & 3) * 8;
  const bf16_t* asrc1 = asrc0 + (size_t)64 * H1_NP;
  const bf16_t* wsrc  = W + (size_t)(tid >> 2) * H1_NP + kb + (tid & 3) * 8;

  auto stage = [&](int buf, int k0) {
    g2lds16(asrc0 + k0, &As[buf][0][0] + tid * 8);
    g2lds16(asrc1 + k0, &As[buf][64][0] + tid * 8);
    g2lds16(wsrc  + k0, &Bs[buf][0][0] + tid * 8);
  };
  stage(0, 0);

  #pragma unroll
  for (int i = 0; i < 4; i++) {                        // 4 * BK32 = 128
    __syncthreads();
    const int cur = i & 1;
    if (i < 3) stage(cur ^ 1, (i + 1) * 32);
    bf16x8 af[2], bfr[4];
    #pragma unroll
    for (int ii = 0; ii < 2; ii++) af[ii]  = *(const bf16x8*)(&As[cur][wm + ii * 16 + la][lk * 8]);
    #pragma unroll
    for (int j = 0; j < 4; j++)    bfr[j] = *(const bf16x8*)(&Bs[cur][j * 16 + la][lk * 8]);
    #pragma unroll
    for (int ii = 0; ii < 2; ii++)
      #pragma unroll
      for (int j = 0; j < 4; j++)
        acc[ii][j] = mfma16(af[ii], bfr[j], acc[ii][j]);
  }

  #pragma unroll
  for (int ii = 0; ii < 2; ii++)
    #pragma unroll
    for (int r = 0; r < 4; r++) {
      int gr = m0 + wm + ii * 16 + lk * 4 + r;
      #pragma unroll
      for (int j = 0; j < 4; j++)
        P[((size_t)split * BATCH + gr) * 64 + j * 16 + la] = acc[ii][j][r];
    }
}

// ---------- stage 5: sum splits + bias + lrelu, then 13-wide output GEMM (VALU) ----------
// grid (BATCH/16); block 256
__global__ __launch_bounds__(256) void finalize_tail(const float* __restrict__ P,
                                                     const float* __restrict__ b2,
                                                     const float* __restrict__ w3,
                                                     const float* __restrict__ b3,
                                                     float* __restrict__ out)
{
  __shared__ float h2s[16][64];
  const int r0 = blockIdx.x * 16;
  const int t = threadIdx.x;
  const int r = t >> 4, c4 = (t & 15) * 4;
  f32x4 s = {};
  #pragma unroll
  for (int sp = 0; sp < KSPLIT; sp++) {
    const f32x4 v = *(const f32x4*)(P + ((size_t)sp * BATCH + r0 + r) * 64 + c4);
    s.x += v.x; s.y += v.y; s.z += v.z; s.w += v.w;
  }
  #pragma unroll
  for (int c = 0; c < 4; c++) {
    int col = c4 + c;
    float v = s[c] + ((col < H2DIM) ? b2[col] : 0.0f);
    h2s[r][col] = fmaxf(v, 0.01f * v);
  }
  __syncthreads();
  if (t < 16 * ODIM) {
    int rr = t / ODIM, o = t - rr * ODIM;
    float acc = b3[o];
    #pragma unroll 10
    for (int k = 0; k < H2DIM; k++) acc += h2s[rr][k] * w3[o * H2DIM + k];
    out[(size_t)(r0 + rr) * ODIM + o] = acc;
  }
}

extern "C" void kernel_launch(void* const* d_in, const int* in_sizes, int n_in,
                              void* d_out, int out_size, void* d_ws, size_t ws_size,
                              hipStream_t stream)
{
  const float* X      = (const float*)d_in[0];
  const float* head_w = (const float*)d_in[1];
  const float* head_b = (const float*)d_in[2];
  const float* conc_w = (const float*)d_in[3];
  const float* conc_b = (const float*)d_in[4];
  const float* w1     = (const float*)d_in[5];
  const float* b1     = (const float*)d_in[6];
  const float* w2     = (const float*)d_in[7];
  const float* b2     = (const float*)d_in[8];
  const float* w3     = (const float*)d_in[9];
  const float* b3     = (const float*)d_in[10];

  char* p = (char*)d_ws;
  auto alloc = [&](size_t bytes) { char* r = p; p += (bytes + 255) & ~(size_t)255; return r; };
  bf16_t* headw_ws = (bf16_t*)alloc((size_t)64 * WH_LD64 * 2);     // 3.75 MB
  bf16_t* concw_ws = (bf16_t*)alloc((size_t)IDIM_NP * IDIM_P * 2); // 10.2 MB
  bf16_t* w1_ws    = (bf16_t*)alloc((size_t)H1_NP * IDIM_P * 2);   // 4.5 MB
  bf16_t* w2_ws    = (bf16_t*)alloc((size_t)128 * H1_NP * 2);      // 0.26 MB
  bf16_t* comb     = (bf16_t*)alloc((size_t)BATCH * IDIM_P * 2);   // 9.0 MB
  bf16_t* zbuf     = (bf16_t*)alloc((size_t)BATCH * IDIM_P * 2);   // 9.0 MB
  bf16_t* h1buf    = (bf16_t*)alloc((size_t)BATCH * H1_NP * 2);    // 4.2 MB
  float*  h2p      = (float*) alloc((size_t)KSPLIT * BATCH * 64 * 4); // 4.0 MB

  auto cgrid = [](size_t n) { return dim3((unsigned)((n + 255) / 256)); };

  convert_headw<<<cgrid((size_t)64 * WH_LD64), 256, 0, stream>>>(head_w, headw_ws);
  convert_pad<<<cgrid((size_t)IDIM_NP * IDIM_P), 256, 0, stream>>>(conc_w, concw_ws, IDIM, IDIM, IDIM_NP, IDIM_P);
  convert_pad<<<cgrid((size_t)H1_NP * IDIM_P), 256, 0, stream>>>(w1, w1_ws, H1DIM, IDIM, H1_NP, IDIM_P);
  convert_pad<<<cgrid((size_t)128 * H1_NP), 256, 0, stream>>>(w2, w2_ws, H2DIM, H1DIM, 128, H1_NP);

  head_gemm2<<<dim3(ROWS / 64, N_HEADS), 256, 0, stream>>>(X, headw_ws, head_b, comb);

  gemm_bt<<<dim3(BATCH / 128, IDIM_NP / 128), 256, 0, stream>>>(
      comb, IDIM_P, concw_ws, IDIM_P, conc_b, zbuf, IDIM_P, IDIM_P, IDIM, 0, 0);
  gemm_bt<<<dim3(BATCH / 128, H1_NP / 128), 256, 0, stream>>>(
      zbuf, IDIM_P, w1_ws, IDIM_P, b1, h1buf, H1_NP, IDIM_P, H1DIM, 1, 0);

  gemm_splitk<<<dim3(BATCH / 128, KSPLIT), 256, 0, stream>>>(h1buf, w2_ws, h2p);
  finalize_tail<<<dim3(BATCH / 16), 256, 0, stream>>>(h2p, b2, w3, b3, (float*)d_out);
}